// Round 1
// baseline (24168.237 us; speedup 1.0000x reference)
//
#include <hip/hip_runtime.h>
#include <hip/hip_bf16.h>
#include <math.h>

#define B_ 128
#define T_ 32
#define IN_ 512
#define H_ 512
#define M_ 16
#define WC_ 20
#define R_ 4
#define RW_ 80
#define NNIN_ 592
#define IFACE_ 163
#define CLIP_ 20.0f
#define EPS_ 1e-6f
#define DELTA_ 5e-6f

__device__ __forceinline__ float sigmoidf_(float x) { return 1.0f / (1.0f + expf(-x)); }
__device__ __forceinline__ float softplusf_(float x) {
    return fmaxf(x, 0.0f) + log1pf(expf(-fabsf(x)));
}

// ---------------------------------------------------------------------------
// C[M x N] = A1[M x K1] @ W1[N x K1]^T + A2[M x K2] @ W2[N x K2]^T + bias1 + bias2
// BM=32, BN=64, BK=16, 256 threads, 2x4 micro-tile. K1,K2 multiples of 16.
// ---------------------------------------------------------------------------
#define BM 32
#define BN 64
#define BK 16

__global__ __launch_bounds__(256) void gemm2(
    const float* __restrict__ A1, int lda1, int K1, const float* __restrict__ W1,
    const float* __restrict__ A2, int lda2, int K2, const float* __restrict__ W2,
    const float* __restrict__ bias1, const float* __restrict__ bias2,
    float* __restrict__ C, int ldc, int M, int N)
{
    __shared__ float As[BK][BM + 1];
    __shared__ float Ws[BK][BN + 4];

    const int bm = blockIdx.y * BM;
    const int bn = blockIdx.x * BN;
    const int tid = threadIdx.x;
    const int tx = tid & 15;   // 16 cols of threads -> 64 N
    const int ty = tid >> 4;   // 16 rows of threads -> 32 M

    float acc[2][4] = {{0.f,0.f,0.f,0.f},{0.f,0.f,0.f,0.f}};

    for (int seg = 0; seg < 2; ++seg) {
        const float* A = seg ? A2 : A1;
        const float* W = seg ? W2 : W1;
        const int K   = seg ? K2 : K1;
        const int lda = seg ? lda2 : lda1;
        if (K == 0 || A == nullptr) continue;

        for (int k0 = 0; k0 < K; k0 += BK) {
            // A tile: 32x16 = 512 elems, 2 per thread
            for (int i = tid; i < BM * BK; i += 256) {
                int m = i >> 4, k = i & 15;
                int gm = bm + m;
                As[k][m] = (gm < M) ? A[(size_t)gm * lda + k0 + k] : 0.f;
            }
            // W tile: 64x16 = 1024 elems, 4 per thread
            for (int i = tid; i < BN * BK; i += 256) {
                int n = i >> 4, k = i & 15;
                int gn = bn + n;
                Ws[k][n] = (gn < N) ? W[(size_t)gn * K + k0 + k] : 0.f;
            }
            __syncthreads();
            #pragma unroll
            for (int k = 0; k < BK; ++k) {
                float a0 = As[k][ty * 2 + 0];
                float a1 = As[k][ty * 2 + 1];
                float w0 = Ws[k][tx * 4 + 0];
                float w1 = Ws[k][tx * 4 + 1];
                float w2 = Ws[k][tx * 4 + 2];
                float w3 = Ws[k][tx * 4 + 3];
                acc[0][0] += a0 * w0; acc[0][1] += a0 * w1;
                acc[0][2] += a0 * w2; acc[0][3] += a0 * w3;
                acc[1][0] += a1 * w0; acc[1][1] += a1 * w1;
                acc[1][2] += a1 * w2; acc[1][3] += a1 * w3;
            }
            __syncthreads();
        }
    }

    #pragma unroll
    for (int i = 0; i < 2; ++i) {
        int gm = bm + ty * 2 + i;
        if (gm >= M) continue;
        #pragma unroll
        for (int j = 0; j < 4; ++j) {
            int gn = bn + tx * 4 + j;
            if (gn >= N) continue;
            float b = 0.f;
            if (bias1) b += bias1[gn];
            if (bias2) b += bias2[gn];
            C[(size_t)gm * ldc + gn] = acc[i][j] + b;
        }
    }
}

// ---------------------------------------------------------------------------
// inp[b, 0:512] = x[b, t, :]; inp[b, 512:592] = 0
// ---------------------------------------------------------------------------
__global__ __launch_bounds__(256) void build_inp(const float* __restrict__ x, int t,
                                                 float* __restrict__ inp)
{
    int idx = blockIdx.x * 256 + threadIdx.x;
    if (idx >= B_ * NNIN_) return;
    int b = idx / NNIN_, j = idx - b * NNIN_;
    inp[idx] = (j < IN_) ? x[(size_t)b * T_ * IN_ + (size_t)t * IN_ + j] : 0.f;
}

// ---------------------------------------------------------------------------
// LSTM pointwise: gates (B x 4H) -> c,h update; optional clipped copy to inp
// ---------------------------------------------------------------------------
__global__ __launch_bounds__(256) void lstm_point(const float* __restrict__ g,
                                                  float* __restrict__ c,
                                                  float* __restrict__ h,
                                                  float* __restrict__ clip_out)
{
    int idx = blockIdx.x * 256 + threadIdx.x;
    if (idx >= B_ * H_) return;
    int b = idx >> 9;
    int j = idx & (H_ - 1);
    const float* gr = g + (size_t)b * 4 * H_;
    float gi = gr[j];
    float gf = gr[j + H_];
    float gg = gr[j + 2 * H_];
    float go = gr[j + 3 * H_];
    float cn = sigmoidf_(gf) * c[idx] + sigmoidf_(gi) * tanhf(gg);
    c[idx] = cn;
    float hn = sigmoidf_(go) * tanhf(cn);
    h[idx] = hn;
    if (clip_out) {
        clip_out[(size_t)b * NNIN_ + j] = fminf(fmaxf(hn, -CLIP_), CLIP_);
    }
}

// ---------------------------------------------------------------------------
// DNC memory step: one block (64 threads = 1 wave) per batch element
// ---------------------------------------------------------------------------
__global__ __launch_bounds__(64) void mem_step(
    const float* __restrict__ iface,  // B x 163
    float* __restrict__ mem,          // B x M x Wc
    float* __restrict__ link,         // B x M x M
    float* __restrict__ prec,         // B x M
    float* __restrict__ rw,           // B x R x M
    float* __restrict__ ww,           // B x M
    float* __restrict__ usage,        // B x M
    float* __restrict__ inp)          // B x 592 (read_vecs -> cols 512:592)
{
    const int b = blockIdx.x;
    const int tid = threadIdx.x;

    __shared__ float sif[IFACE_];
    __shared__ float modes[R_][3];
    __shared__ float us[M_], wwold[M_], wwnew[M_], precold[M_];
    __shared__ float rwold[R_][M_], rwnewS[R_][M_];
    __shared__ float lnk[M_][M_];
    __shared__ float memS[M_][WC_];
    __shared__ float wcw[M_], allocS[M_], rcw[R_][M_];
    __shared__ float uu[M_];
    __shared__ int   phi[M_];
    __shared__ float sumww;

    const float* ifr = iface + (size_t)b * IFACE_;
    // load + transform interface vector
    for (int i = tid; i < IFACE_; i += 64) {
        float v = ifr[i];
        float r;
        if (i < 80)        r = tanhf(v);        // read keys
        else if (i < 84)   r = softplusf_(v);   // read strengths
        else if (i < 104)  r = tanhf(v);        // write key
        else if (i < 105)  r = softplusf_(v);   // write strength
        else if (i < 125)  r = sigmoidf_(v);    // erase
        else if (i < 145)  r = tanhf(v);        // write vector
        else if (i < 149)  r = sigmoidf_(v);    // free gates
        else if (i < 151)  r = sigmoidf_(v);    // alloc gate, write gate
        else               r = v;               // read modes (raw)
        sif[i] = r;
    }
    // load states
    if (tid < M_) {
        us[tid]      = usage[(size_t)b * M_ + tid];
        wwold[tid]   = ww[(size_t)b * M_ + tid];
        precold[tid] = prec[(size_t)b * M_ + tid];
    }
    for (int i = tid; i < R_ * M_; i += 64) rwold[i >> 4][i & 15] = rw[(size_t)b * R_ * M_ + i];
    for (int i = tid; i < M_ * M_; i += 64) lnk[i >> 4][i & 15] = link[(size_t)b * M_ * M_ + i];
    for (int i = tid; i < M_ * WC_; i += 64) memS[i / WC_][i % WC_] = mem[(size_t)b * M_ * WC_ + i];
    __syncthreads();

    // read-mode softmax
    if (tid < R_) {
        float a0 = sif[151 + tid * 3], a1 = sif[152 + tid * 3], a2 = sif[153 + tid * 3];
        float mx = fmaxf(a0, fmaxf(a1, a2));
        float e0 = expf(a0 - mx), e1 = expf(a1 - mx), e2 = expf(a2 - mx);
        float s = e0 + e1 + e2;
        modes[tid][0] = e0 / s; modes[tid][1] = e1 / s; modes[tid][2] = e2 / s;
    }
    // usage update (uses OLD ww, OLD rw)
    if (tid < M_) {
        float u = us[tid];
        u = u + (1.f - u) * wwold[tid];
        float psi = 1.f;
        #pragma unroll
        for (int r = 0; r < R_; ++r) psi *= (1.f - sif[145 + r] * rwold[r][tid]);
        u *= psi;
        us[tid] = u;
    }
    // write content weighting (OLD memory)
    if (tid < M_) {
        float kn2 = 0.f, mn2 = 0.f, dot = 0.f;
        #pragma unroll
        for (int w = 0; w < WC_; ++w) {
            float kv = sif[84 + w], mv = memS[tid][w];
            kn2 += kv * kv; mn2 += mv * mv; dot += kv * mv;
        }
        float c = dot / ((sqrtf(kn2) + EPS_) * (sqrtf(mn2) + EPS_));
        wcw[tid] = c * sif[104]; // * write_str
    }
    __syncthreads();

    if (tid == 0) {
        // softmax(wcw)
        float mx = -1e30f;
        for (int m = 0; m < M_; ++m) mx = fmaxf(mx, wcw[m]);
        float s = 0.f;
        for (int m = 0; m < M_; ++m) { wcw[m] = expf(wcw[m] - mx); s += wcw[m]; }
        for (int m = 0; m < M_; ++m) wcw[m] /= s;
        // allocation weighting: stable ascending sort of u
        for (int m = 0; m < M_; ++m) { uu[m] = DELTA_ + (1.f - DELTA_) * us[m]; phi[m] = m; }
        for (int j = 1; j < M_; ++j) {
            float key = uu[j]; int kp = phi[j];
            int i2 = j - 1;
            while (i2 >= 0 && uu[i2] > key) { uu[i2 + 1] = uu[i2]; phi[i2 + 1] = phi[i2]; --i2; }
            uu[i2 + 1] = key; phi[i2 + 1] = kp;
        }
        float prod = 1.f;
        for (int j = 0; j < M_; ++j) {
            float sa = (1.f - uu[j]) * prod;
            prod *= uu[j];
            allocS[phi[j]] = sa;
        }
    }
    __syncthreads();

    // new write weighting
    if (tid < M_) {
        wwnew[tid] = sif[150] * (sif[149] * allocS[tid] + (1.f - sif[149]) * wcw[tid]);
    }
    __syncthreads();

    if (tid == 0) {
        float s = 0.f;
        for (int m = 0; m < M_; ++m) s += wwnew[m];
        sumww = s;
    }
    // memory update
    for (int i = tid; i < M_ * WC_; i += 64) {
        int m = i / WC_, w = i % WC_;
        float nm = memS[m][w] * (1.f - wwnew[m] * sif[105 + w]) + wwnew[m] * sif[125 + w];
        memS[m][w] = nm;
        mem[(size_t)b * M_ * WC_ + i] = nm;
    }
    __syncthreads();

    // link update (uses OLD prec), then prec/usage/ww writeback
    for (int idx = tid; idx < M_ * M_; idx += 64) {
        int i = idx >> 4, j = idx & 15;
        float v = (1.f - wwnew[i] - wwnew[j]) * lnk[i][j] + wwnew[i] * precold[j];
        if (i == j) v = 0.f;
        lnk[i][j] = v;
        link[(size_t)b * M_ * M_ + idx] = v;
    }
    if (tid < M_) {
        prec[(size_t)b * M_ + tid] = (1.f - sumww) * precold[tid] + wwnew[tid];
        usage[(size_t)b * M_ + tid] = us[tid];
        ww[(size_t)b * M_ + tid] = wwnew[tid];
    }
    __syncthreads();

    // read content weighting (NEW memory): thread = (r, m)
    {
        int r = tid >> 4, m = tid & 15;
        float kn2 = 0.f, mn2 = 0.f, dot = 0.f;
        #pragma unroll
        for (int w = 0; w < WC_; ++w) {
            float kv = sif[r * WC_ + w], mv = memS[m][w];
            kn2 += kv * kv; mn2 += mv * mv; dot += kv * mv;
        }
        float c = dot / ((sqrtf(kn2) + EPS_) * (sqrtf(mn2) + EPS_));
        rcw[r][m] = c * sif[80 + r];
    }
    __syncthreads();
    if (tid < R_) {
        float mx = -1e30f;
        for (int m = 0; m < M_; ++m) mx = fmaxf(mx, rcw[tid][m]);
        float s = 0.f;
        for (int m = 0; m < M_; ++m) { rcw[tid][m] = expf(rcw[tid][m] - mx); s += rcw[tid][m]; }
        for (int m = 0; m < M_; ++m) rcw[tid][m] /= s;
    }
    __syncthreads();

    // new read weights: modes over {bwd, fwd, content}, NEW link, OLD rw
    {
        int r = tid >> 4, m = tid & 15;
        float fwd = 0.f, bwd = 0.f;
        #pragma unroll
        for (int j = 0; j < M_; ++j) fwd += lnk[m][j] * rwold[r][j];
        #pragma unroll
        for (int i = 0; i < M_; ++i) bwd += rwold[r][i] * lnk[i][m];
        float v = modes[r][0] * bwd + modes[r][1] * fwd + modes[r][2] * rcw[r][m];
        rwnewS[r][m] = v;
        rw[(size_t)b * R_ * M_ + tid] = v;
    }
    __syncthreads();

    // read vectors -> inp[b, 512 + r*20 + w]
    for (int i = tid; i < RW_; i += 64) {
        int r = i / WC_, w = i - r * WC_;
        float s = 0.f;
        #pragma unroll
        for (int m = 0; m < M_; ++m) s += rwnewS[r][m] * memS[m][w];
        inp[(size_t)b * NNIN_ + IN_ + i] = s;
    }
}

// ---------------------------------------------------------------------------
extern "C" void kernel_launch(void* const* d_in, const int* in_sizes, int n_in,
                              void* d_out, int out_size, void* d_ws, size_t ws_size,
                              hipStream_t stream)
{
    const float* x       = (const float*)d_in[0];
    const float* W_ih0   = (const float*)d_in[1];   // L x 2048 x 592
    const float* W_hh0   = (const float*)d_in[2];   // L x 2048 x 512
    const float* b_ih0   = (const float*)d_in[3];   // L x 2048
    const float* b_hh0   = (const float*)d_in[4];
    const float* W_ih1   = (const float*)d_in[5];   // L x 2048 x 512
    const float* W_hh1   = (const float*)d_in[6];
    const float* b_ih1   = (const float*)d_in[7];
    const float* b_hh1   = (const float*)d_in[8];
    const float* W_iface = (const float*)d_in[9];   // L x 163 x 512
    const float* b_iface = (const float*)d_in[10];  // L x 163
    const float* W_out   = (const float*)d_in[11];  // 512 x 592
    const float* b_out   = (const float*)d_in[12];  // 512
    float* out = (float*)d_out;

    float* ws = (float*)d_ws;
    // state (zero-initialized region, contiguous)
    float* h      = ws;                       // 2*2*128*512   = 262144
    float* c      = h + 262144;               // 262144
    float* memv   = c + 262144;               // 2*128*320     = 81920
    float* linkv  = memv + 81920;             // 2*128*256     = 65536
    float* precv  = linkv + 65536;            // 2*128*16      = 4096
    float* rwv    = precv + 4096;             // 2*128*64      = 16384
    float* wwv    = rwv + 16384;              // 4096
    float* usagev = wwv + 4096;               // 4096
    const size_t zeroN = 262144ull * 2 + 81920 + 65536 + 4096 + 16384 + 4096 + 4096;
    // scratch (fully written before read)
    float* inp    = usagev + 4096;            // 128*592 = 75776
    float* gates  = inp + 75776;              // 128*2048 = 262144
    float* ifacev = gates + 262144;           // 128*163 = 20864

    hipMemsetAsync(ws, 0, zeroN * sizeof(float), stream);

    const dim3 gemmThreads(256);
    const dim3 gBig(2048 / BN, B_ / BM);        // 32 x 4
    const dim3 gIface((IFACE_ + BN - 1) / BN, B_ / BM);
    const dim3 gOut(IN_ / BN, B_ / BM);

    for (int t = 0; t < T_; ++t) {
        build_inp<<<(B_ * NNIN_ + 255) / 256, 256, 0, stream>>>(x, t, inp);
        for (int l = 0; l < 2; ++l) {
            float* hl0 = h + (size_t)(l * 2 + 0) * B_ * H_;
            float* hl1 = h + (size_t)(l * 2 + 1) * B_ * H_;
            float* cl0 = c + (size_t)(l * 2 + 0) * B_ * H_;
            float* cl1 = c + (size_t)(l * 2 + 1) * B_ * H_;

            // cell A gates
            gemm2<<<gBig, gemmThreads, 0, stream>>>(
                inp, NNIN_, NNIN_, W_ih0 + (size_t)l * 2048 * NNIN_,
                hl0, H_, H_, W_hh0 + (size_t)l * 2048 * H_,
                b_ih0 + (size_t)l * 2048, b_hh0 + (size_t)l * 2048,
                gates, 2048, B_, 2048);
            lstm_point<<<(B_ * H_ + 255) / 256, 256, 0, stream>>>(gates, cl0, hl0, nullptr);

            // cell B gates
            gemm2<<<gBig, gemmThreads, 0, stream>>>(
                hl0, H_, H_, W_ih1 + (size_t)l * 2048 * H_,
                hl1, H_, H_, W_hh1 + (size_t)l * 2048 * H_,
                b_ih1 + (size_t)l * 2048, b_hh1 + (size_t)l * 2048,
                gates, 2048, B_, 2048);
            lstm_point<<<(B_ * H_ + 255) / 256, 256, 0, stream>>>(gates, cl1, hl1, inp);

            // interface projection (reads out = inp[:, :512])
            gemm2<<<gIface, gemmThreads, 0, stream>>>(
                inp, NNIN_, H_, W_iface + (size_t)l * IFACE_ * H_,
                nullptr, 0, 0, nullptr,
                b_iface + (size_t)l * IFACE_, nullptr,
                ifacev, IFACE_, B_, IFACE_);

            mem_step<<<B_, 64, 0, stream>>>(
                ifacev,
                memv + (size_t)l * B_ * M_ * WC_,
                linkv + (size_t)l * B_ * M_ * M_,
                precv + (size_t)l * B_ * M_,
                rwv + (size_t)l * B_ * R_ * M_,
                wwv + (size_t)l * B_ * M_,
                usagev + (size_t)l * B_ * M_,
                inp);
        }
        // y_t = [out1, rv1] @ W_out^T + b_out
        gemm2<<<gOut, gemmThreads, 0, stream>>>(
            inp, NNIN_, NNIN_, W_out,
            nullptr, 0, 0, nullptr,
            b_out, nullptr,
            out + (size_t)t * IN_, T_ * IN_, B_, IN_);
    }
}

// Round 2
// 11905.691 us; speedup vs baseline: 2.0300x; 2.0300x over previous
//
#include <hip/hip_runtime.h>
#include <hip/hip_bf16.h>
#include <math.h>

#define B_ 128
#define T_ 32
#define IN_ 512
#define H_ 512
#define M_ 16
#define WC_ 20
#define R_ 4
#define RW_ 80
#define NNIN_ 592
#define IFACE_ 163
#define IFP_ 192      // iface N padded to 192 (6 tiles of 32)
#define K1P_ 1120     // 592+512 padded to /16.. (1104->1120, mult of 16)
#define K2P_ 1024
#define KOP_ 608      // 592 -> 608
#define CLIP_ 20.0f
#define EPS_ 1e-6f
#define DELTA_ 5e-6f

typedef __bf16 bf16x8 __attribute__((ext_vector_type(8)));
typedef float f32x16 __attribute__((ext_vector_type(16)));

__device__ __forceinline__ float sigmoidf_(float x) { return 1.0f / (1.0f + expf(-x)); }
__device__ __forceinline__ float softplusf_(float x) {
    return fmaxf(x, 0.0f) + log1pf(expf(-fabsf(x)));
}

// ---------------------------------------------------------------------------
// split fp32 -> bf16 hi/lo
// ---------------------------------------------------------------------------
__device__ __forceinline__ void split2(float v, __bf16* hp, __bf16* lp) {
    __bf16 h = (__bf16)v;
    *hp = h;
    *lp = (__bf16)(v - (float)h);
}

// ---------------------------------------------------------------------------
// Weight conversion: dst[n][k] (k<K1: src1, k<K1+K2: src2, else 0) -> hi/lo
// rows n >= Nsrc are zero (for iface N padding)
// ---------------------------------------------------------------------------
__global__ __launch_bounds__(256) void conv_split(
    const float* __restrict__ s1, int K1, const float* __restrict__ s2, int K2,
    int Nsrc, __bf16* __restrict__ hi, __bf16* __restrict__ lo, int Kd)
{
    int k = blockIdx.x * 256 + threadIdx.x;
    int n = blockIdx.y;
    if (k >= Kd) return;
    float v = 0.f;
    if (n < Nsrc) {
        if (k < K1) v = s1[(size_t)n * K1 + k];
        else if (k < K1 + K2) v = s2[(size_t)n * K2 + (k - K1)];
    }
    __bf16 h = (__bf16)v;
    hi[(size_t)n * Kd + k] = h;
    lo[(size_t)n * Kd + k] = (__bf16)(v - (float)h);
}

__global__ __launch_bounds__(192) void conv_biasif(const float* __restrict__ b_iface,
                                                   float* __restrict__ dst)
{
    int l = blockIdx.x, k = threadIdx.x;
    dst[l * IFP_ + k] = (k < IFACE_) ? b_iface[l * IFACE_ + k] : 0.f;
}

// ---------------------------------------------------------------------------
// x_t -> A1buf_0 cols [0,512) as bf16 hi/lo (cols 512..591 stay 0 = last_read)
// ---------------------------------------------------------------------------
__global__ __launch_bounds__(256) void build_inp(const float* __restrict__ x, int t,
                                                 __bf16* __restrict__ a1h,
                                                 __bf16* __restrict__ a1l)
{
    int idx = blockIdx.x * 256 + threadIdx.x;
    if (idx >= B_ * IN_) return;
    int b = idx >> 9, j = idx & 511;
    float v = x[(size_t)b * T_ * IN_ + (size_t)t * IN_ + j];
    __bf16 h = (__bf16)v;
    a1h[b * K1P_ + j] = h;
    a1l[b * K1P_ + j] = (__bf16)(v - (float)h);
}

// ---------------------------------------------------------------------------
// Fused LSTM-cell GEMM: one wave per (32-batch x 32-hidden) tile; gates at
// N-offsets {0,512,1024,1536}. Split-bf16 3-pass MFMA (32x32x16).
// Epilogue: LSTM pointwise, c update, h -> bf16 hi/lo dests.
// ---------------------------------------------------------------------------
__global__ __launch_bounds__(64) void gemm_lstm(
    const __bf16* __restrict__ Ah, const __bf16* __restrict__ Al, const int KS,
    const __bf16* __restrict__ Wh, const __bf16* __restrict__ Wl,
    const float* __restrict__ b1, const float* __restrict__ b2,
    float* __restrict__ cst,
    __bf16* __restrict__ d1h, __bf16* __restrict__ d1l, int st1,
    __bf16* __restrict__ d2h, __bf16* __restrict__ d2l, int st2)
{
    const int lane = threadIdx.x;
    const int l31 = lane & 31, lhi = lane >> 5;
    const int j0 = blockIdx.x * 32;
    const int m0 = blockIdx.y * 32;

    f32x16 acc[4];
    #pragma unroll
    for (int g = 0; g < 4; ++g)
        #pragma unroll
        for (int i = 0; i < 16; ++i) acc[g][i] = 0.f;

    int aoff = (m0 + l31) * KS + lhi * 8;
    int woff[4];
    #pragma unroll
    for (int g = 0; g < 4; ++g) woff[g] = (g * 512 + j0 + l31) * KS + lhi * 8;

    for (int k = 0; k < KS; k += 16) {
        bf16x8 ah = *(const bf16x8*)(Ah + aoff);
        bf16x8 al = *(const bf16x8*)(Al + aoff);
        aoff += 16;
        #pragma unroll
        for (int g = 0; g < 4; ++g) {
            bf16x8 wh = *(const bf16x8*)(Wh + woff[g]);
            bf16x8 wl = *(const bf16x8*)(Wl + woff[g]);
            woff[g] += 16;
            acc[g] = __builtin_amdgcn_mfma_f32_32x32x16_bf16(ah, wh, acc[g], 0, 0, 0);
            acc[g] = __builtin_amdgcn_mfma_f32_32x32x16_bf16(al, wh, acc[g], 0, 0, 0);
            acc[g] = __builtin_amdgcn_mfma_f32_32x32x16_bf16(ah, wl, acc[g], 0, 0, 0);
        }
    }

    const int col = j0 + l31;
    const float bi = b1[col] + b2[col];
    const float bff = b1[col + 512] + b2[col + 512];
    const float bg = b1[col + 1024] + b2[col + 1024];
    const float bo = b1[col + 1536] + b2[col + 1536];

    #pragma unroll
    for (int r = 0; r < 16; ++r) {
        const int row = (r & 3) + 8 * (r >> 2) + 4 * lhi;
        const int bidx = m0 + row;
        float gi = acc[0][r] + bi;
        float gf = acc[1][r] + bff;
        float gg = acc[2][r] + bg;
        float go = acc[3][r] + bo;
        float cold = cst[bidx * H_ + col];
        float cn = sigmoidf_(gf) * cold + sigmoidf_(gi) * tanhf(gg);
        cst[bidx * H_ + col] = cn;
        float h = sigmoidf_(go) * tanhf(cn);
        split2(h, &d1h[bidx * st1 + col], &d1l[bidx * st1 + col]);
        if (d2h) {
            float hc = fminf(fmaxf(h, -CLIP_), CLIP_);
            split2(hc, &d2h[bidx * st2 + col], &d2l[bidx * st2 + col]);
        }
    }
}

// ---------------------------------------------------------------------------
// Plain split-bf16 MFMA GEMM: C[m][n] = A@W^T + bias (fp32 out)
// ---------------------------------------------------------------------------
__global__ __launch_bounds__(64) void gemm_plain(
    const __bf16* __restrict__ Ah, const __bf16* __restrict__ Al, const int AS,
    const __bf16* __restrict__ Wh, const __bf16* __restrict__ Wl, const int WS,
    const int K, const float* __restrict__ bias,
    float* __restrict__ C, const int ldc)
{
    const int lane = threadIdx.x;
    const int l31 = lane & 31, lhi = lane >> 5;
    const int n0 = blockIdx.x * 32;
    const int m0 = blockIdx.y * 32;

    f32x16 acc;
    #pragma unroll
    for (int i = 0; i < 16; ++i) acc[i] = 0.f;

    int aoff = (m0 + l31) * AS + lhi * 8;
    int woff = (n0 + l31) * WS + lhi * 8;

    for (int k = 0; k < K; k += 16) {
        bf16x8 ah = *(const bf16x8*)(Ah + aoff);
        bf16x8 al = *(const bf16x8*)(Al + aoff);
        bf16x8 wh = *(const bf16x8*)(Wh + woff);
        bf16x8 wl = *(const bf16x8*)(Wl + woff);
        aoff += 16; woff += 16;
        acc = __builtin_amdgcn_mfma_f32_32x32x16_bf16(ah, wh, acc, 0, 0, 0);
        acc = __builtin_amdgcn_mfma_f32_32x32x16_bf16(al, wh, acc, 0, 0, 0);
        acc = __builtin_amdgcn_mfma_f32_32x32x16_bf16(ah, wl, acc, 0, 0, 0);
    }

    const int col = n0 + l31;
    const float bv = bias[col];
    #pragma unroll
    for (int r = 0; r < 16; ++r) {
        const int row = (r & 3) + 8 * (r >> 2) + 4 * lhi;
        C[(size_t)(m0 + row) * ldc + col] = acc[r] + bv;
    }
}

// ---------------------------------------------------------------------------
// DNC memory step: one wave per batch element + state copy-backs
// ---------------------------------------------------------------------------
__global__ __launch_bounds__(64) void mem_step(
    const float* __restrict__ iface,  // B x 192
    float* __restrict__ mem, float* __restrict__ link, float* __restrict__ prec,
    float* __restrict__ rw, float* __restrict__ ww, float* __restrict__ usage,
    __bf16* __restrict__ dsth, __bf16* __restrict__ dstl, int dstst, // rv -> cols 512+
    __bf16* __restrict__ a1h, __bf16* __restrict__ a1l,   // h0 copy dest (col 592)
    __bf16* __restrict__ a2h, __bf16* __restrict__ a2l,   // A2buf (src h0 / dst h1)
    const __bf16* __restrict__ h1h, const __bf16* __restrict__ h1l)
{
    const int b = blockIdx.x;
    const int tid = threadIdx.x;

    __shared__ float sif[IFACE_];
    __shared__ float modes[R_][3];
    __shared__ float us[M_], wwold[M_], wwnew[M_], precold[M_];
    __shared__ float rwold[R_][M_], rwnewS[R_][M_];
    __shared__ float lnk[M_][M_];
    __shared__ float memS[M_][WC_];
    __shared__ float wcw[M_], allocS[M_], rcw[R_][M_];
    __shared__ float uu[M_];
    __shared__ int   phi[M_];
    __shared__ float sumww;

    const float* ifr = iface + (size_t)b * IFP_;
    for (int i = tid; i < IFACE_; i += 64) {
        float v = ifr[i];
        float r;
        if (i < 80)        r = tanhf(v);
        else if (i < 84)   r = softplusf_(v);
        else if (i < 104)  r = tanhf(v);
        else if (i < 105)  r = softplusf_(v);
        else if (i < 125)  r = sigmoidf_(v);
        else if (i < 145)  r = tanhf(v);
        else if (i < 149)  r = sigmoidf_(v);
        else if (i < 151)  r = sigmoidf_(v);
        else               r = v;
        sif[i] = r;
    }
    if (tid < M_) {
        us[tid]      = usage[(size_t)b * M_ + tid];
        wwold[tid]   = ww[(size_t)b * M_ + tid];
        precold[tid] = prec[(size_t)b * M_ + tid];
    }
    for (int i = tid; i < R_ * M_; i += 64) rwold[i >> 4][i & 15] = rw[(size_t)b * R_ * M_ + i];
    for (int i = tid; i < M_ * M_; i += 64) lnk[i >> 4][i & 15] = link[(size_t)b * M_ * M_ + i];
    for (int i = tid; i < M_ * WC_; i += 64) memS[i / WC_][i % WC_] = mem[(size_t)b * M_ * WC_ + i];
    __syncthreads();

    if (tid < R_) {
        float a0 = sif[151 + tid * 3], a1 = sif[152 + tid * 3], a2 = sif[153 + tid * 3];
        float mx = fmaxf(a0, fmaxf(a1, a2));
        float e0 = expf(a0 - mx), e1 = expf(a1 - mx), e2 = expf(a2 - mx);
        float s = e0 + e1 + e2;
        modes[tid][0] = e0 / s; modes[tid][1] = e1 / s; modes[tid][2] = e2 / s;
    }
    if (tid < M_) {
        float u = us[tid];
        u = u + (1.f - u) * wwold[tid];
        float psi = 1.f;
        #pragma unroll
        for (int r = 0; r < R_; ++r) psi *= (1.f - sif[145 + r] * rwold[r][tid]);
        u *= psi;
        us[tid] = u;
    }
    if (tid < M_) {
        float kn2 = 0.f, mn2 = 0.f, dot = 0.f;
        #pragma unroll
        for (int w = 0; w < WC_; ++w) {
            float kv = sif[84 + w], mv = memS[tid][w];
            kn2 += kv * kv; mn2 += mv * mv; dot += kv * mv;
        }
        float c = dot / ((sqrtf(kn2) + EPS_) * (sqrtf(mn2) + EPS_));
        wcw[tid] = c * sif[104];
    }
    __syncthreads();

    if (tid == 0) {
        float mx = -1e30f;
        for (int m = 0; m < M_; ++m) mx = fmaxf(mx, wcw[m]);
        float s = 0.f;
        for (int m = 0; m < M_; ++m) { wcw[m] = expf(wcw[m] - mx); s += wcw[m]; }
        for (int m = 0; m < M_; ++m) wcw[m] /= s;
        for (int m = 0; m < M_; ++m) { uu[m] = DELTA_ + (1.f - DELTA_) * us[m]; phi[m] = m; }
        for (int j = 1; j < M_; ++j) {
            float key = uu[j]; int kp = phi[j];
            int i2 = j - 1;
            while (i2 >= 0 && uu[i2] > key) { uu[i2 + 1] = uu[i2]; phi[i2 + 1] = phi[i2]; --i2; }
            uu[i2 + 1] = key; phi[i2 + 1] = kp;
        }
        float prod = 1.f;
        for (int j = 0; j < M_; ++j) {
            float sa = (1.f - uu[j]) * prod;
            prod *= uu[j];
            allocS[phi[j]] = sa;
        }
    }
    __syncthreads();

    if (tid < M_) {
        wwnew[tid] = sif[150] * (sif[149] * allocS[tid] + (1.f - sif[149]) * wcw[tid]);
    }
    __syncthreads();

    if (tid == 0) {
        float s = 0.f;
        for (int m = 0; m < M_; ++m) s += wwnew[m];
        sumww = s;
    }
    for (int i = tid; i < M_ * WC_; i += 64) {
        int m = i / WC_, w = i % WC_;
        float nm = memS[m][w] * (1.f - wwnew[m] * sif[105 + w]) + wwnew[m] * sif[125 + w];
        memS[m][w] = nm;
        mem[(size_t)b * M_ * WC_ + i] = nm;
    }
    __syncthreads();

    for (int idx = tid; idx < M_ * M_; idx += 64) {
        int i = idx >> 4, j = idx & 15;
        float v = (1.f - wwnew[i] - wwnew[j]) * lnk[i][j] + wwnew[i] * precold[j];
        if (i == j) v = 0.f;
        lnk[i][j] = v;
        link[(size_t)b * M_ * M_ + idx] = v;
    }
    if (tid < M_) {
        prec[(size_t)b * M_ + tid] = (1.f - sumww) * precold[tid] + wwnew[tid];
        usage[(size_t)b * M_ + tid] = us[tid];
        ww[(size_t)b * M_ + tid] = wwnew[tid];
    }
    __syncthreads();

    {
        int r = tid >> 4, m = tid & 15;
        float kn2 = 0.f, mn2 = 0.f, dot = 0.f;
        #pragma unroll
        for (int w = 0; w < WC_; ++w) {
            float kv = sif[r * WC_ + w], mv = memS[m][w];
            kn2 += kv * kv; mn2 += mv * mv; dot += kv * mv;
        }
        float c = dot / ((sqrtf(kn2) + EPS_) * (sqrtf(mn2) + EPS_));
        rcw[r][m] = c * sif[80 + r];
    }
    __syncthreads();
    if (tid < R_) {
        float mx = -1e30f;
        for (int m = 0; m < M_; ++m) mx = fmaxf(mx, rcw[tid][m]);
        float s = 0.f;
        for (int m = 0; m < M_; ++m) { rcw[tid][m] = expf(rcw[tid][m] - mx); s += rcw[tid][m]; }
        for (int m = 0; m < M_; ++m) rcw[tid][m] /= s;
    }
    __syncthreads();

    {
        int r = tid >> 4, m = tid & 15;
        float fwd = 0.f, bwd = 0.f;
        #pragma unroll
        for (int j = 0; j < M_; ++j) fwd += lnk[m][j] * rwold[r][j];
        #pragma unroll
        for (int i = 0; i < M_; ++i) bwd += rwold[r][i] * lnk[i][m];
        float v = modes[r][0] * bwd + modes[r][1] * fwd + modes[r][2] * rcw[r][m];
        rwnewS[r][m] = v;
        rw[(size_t)b * R_ * M_ + tid] = v;
    }
    __syncthreads();

    // read vectors -> dst cols [512, 592) as bf16 hi/lo
    for (int i = tid; i < RW_; i += 64) {
        int r = i / WC_, w = i - r * WC_;
        float s = 0.f;
        #pragma unroll
        for (int m = 0; m < M_; ++m) s += rwnewS[r][m] * memS[m][w];
        split2(s, &dsth[(size_t)b * dstst + IN_ + i], &dstl[(size_t)b * dstst + IN_ + i]);
    }

    // state copy-backs: h0 (A2buf[0:512]) -> A1buf[592:1104]; h1st -> A2buf[512:1024]
    for (int j = tid; j < H_; j += 64) {
        a1h[(size_t)b * K1P_ + NNIN_ + j] = a2h[(size_t)b * K2P_ + j];
        a1l[(size_t)b * K1P_ + NNIN_ + j] = a2l[(size_t)b * K2P_ + j];
        a2h[(size_t)b * K2P_ + H_ + j] = h1h[(size_t)b * H_ + j];
        a2l[(size_t)b * K2P_ + H_ + j] = h1l[(size_t)b * H_ + j];
    }
}

// ---------------------------------------------------------------------------
extern "C" void kernel_launch(void* const* d_in, const int* in_sizes, int n_in,
                              void* d_out, int out_size, void* d_ws, size_t ws_size,
                              hipStream_t stream)
{
    const float* x       = (const float*)d_in[0];
    const float* W_ih0   = (const float*)d_in[1];   // L x 2048 x 592
    const float* W_hh0   = (const float*)d_in[2];   // L x 2048 x 512
    const float* b_ih0   = (const float*)d_in[3];
    const float* b_hh0   = (const float*)d_in[4];
    const float* W_ih1   = (const float*)d_in[5];   // L x 2048 x 512
    const float* W_hh1   = (const float*)d_in[6];
    const float* b_ih1   = (const float*)d_in[7];
    const float* b_hh1   = (const float*)d_in[8];
    const float* W_iface = (const float*)d_in[9];   // L x 163 x 512
    const float* b_iface = (const float*)d_in[10];
    const float* W_out   = (const float*)d_in[11];  // 512 x 592
    const float* b_out   = (const float*)d_in[12];
    float* out = (float*)d_out;

    char* p = (char*)d_ws;
    auto alloc = [&](size_t bytes) { char* r = p; p += (bytes + 255) & ~(size_t)255; return r; };

    // ---- zero zone (memset each call) ----
    char* zstart = p;
    __bf16* a1h[2]; __bf16* a1l[2]; __bf16* a2h[2]; __bf16* a2l[2];
    __bf16* h1h[2]; __bf16* h1l[2];
    for (int l = 0; l < 2; ++l) { a1h[l] = (__bf16*)alloc(B_ * K1P_ * 2); a1l[l] = (__bf16*)alloc(B_ * K1P_ * 2); }
    for (int l = 0; l < 2; ++l) { a2h[l] = (__bf16*)alloc(B_ * K2P_ * 2); a2l[l] = (__bf16*)alloc(B_ * K2P_ * 2); }
    for (int l = 0; l < 2; ++l) { h1h[l] = (__bf16*)alloc(B_ * H_ * 2);   h1l[l] = (__bf16*)alloc(B_ * H_ * 2); }
    __bf16* yinh = (__bf16*)alloc(B_ * KOP_ * 2);
    __bf16* yinl = (__bf16*)alloc(B_ * KOP_ * 2);
    float* cbuf   = (float*)alloc(4ull * B_ * H_ * 4);            // [l*2+cell][B][H]
    float* memv   = (float*)alloc(2ull * B_ * M_ * WC_ * 4);
    float* linkv  = (float*)alloc(2ull * B_ * M_ * M_ * 4);
    float* precv  = (float*)alloc(2ull * B_ * M_ * 4);
    float* rwv    = (float*)alloc(2ull * B_ * R_ * M_ * 4);
    float* wwv    = (float*)alloc(2ull * B_ * M_ * 4);
    float* usagev = (float*)alloc(2ull * B_ * M_ * 4);
    size_t zbytes = (size_t)(p - zstart);

    // ---- non-zero scratch ----
    float* ifacev = (float*)alloc(B_ * IFP_ * 4);
    __bf16* w1h[2]; __bf16* w1l[2]; __bf16* w2h[2]; __bf16* w2l[2];
    __bf16* wifh[2]; __bf16* wifl[2];
    for (int l = 0; l < 2; ++l) { w1h[l] = (__bf16*)alloc(2048ull * K1P_ * 2); w1l[l] = (__bf16*)alloc(2048ull * K1P_ * 2); }
    for (int l = 0; l < 2; ++l) { w2h[l] = (__bf16*)alloc(2048ull * K2P_ * 2); w2l[l] = (__bf16*)alloc(2048ull * K2P_ * 2); }
    for (int l = 0; l < 2; ++l) { wifh[l] = (__bf16*)alloc((size_t)IFP_ * 512 * 2); wifl[l] = (__bf16*)alloc((size_t)IFP_ * 512 * 2); }
    __bf16* wouth = (__bf16*)alloc(512ull * KOP_ * 2);
    __bf16* woutl = (__bf16*)alloc(512ull * KOP_ * 2);
    float* biasif = (float*)alloc(2ull * IFP_ * 4);

    hipMemsetAsync(zstart, 0, zbytes, stream);

    // ---- weight conversion (split bf16 hi/lo, concat + pad) ----
    for (int l = 0; l < 2; ++l) {
        conv_split<<<dim3((K1P_ + 255) / 256, 2048), 256, 0, stream>>>(
            W_ih0 + (size_t)l * 2048 * NNIN_, NNIN_, W_hh0 + (size_t)l * 2048 * H_, H_,
            2048, w1h[l], w1l[l], K1P_);
        conv_split<<<dim3((K2P_ + 255) / 256, 2048), 256, 0, stream>>>(
            W_ih1 + (size_t)l * 2048 * H_, H_, W_hh1 + (size_t)l * 2048 * H_, H_,
            2048, w2h[l], w2l[l], K2P_);
        conv_split<<<dim3(2, IFP_), 256, 0, stream>>>(
            W_iface + (size_t)l * IFACE_ * H_, H_, nullptr, 0,
            IFACE_, wifh[l], wifl[l], H_);
        // note: grid.y = IFP_ rows, rows >= 163 zeroed via Nsrc
    }
    conv_split<<<dim3((KOP_ + 255) / 256, 512), 256, 0, stream>>>(
        W_out, NNIN_, nullptr, 0, 512, wouth, woutl, KOP_);
    conv_biasif<<<2, 192, 0, stream>>>(b_iface, biasif);

    const dim3 gBig(16, 4), gIf(6, 4), gOut(16, 4);

    for (int t = 0; t < T_; ++t) {
        build_inp<<<(B_ * IN_ + 255) / 256, 256, 0, stream>>>(x, t, a1h[0], a1l[0]);
        for (int l = 0; l < 2; ++l) {
            float* c0 = cbuf + (size_t)(l * 2 + 0) * B_ * H_;
            float* c1 = cbuf + (size_t)(l * 2 + 1) * B_ * H_;
            __bf16* cliph = (l == 0) ? a1h[1] : yinh;
            __bf16* clipl = (l == 0) ? a1l[1] : yinl;
            const int clipst = (l == 0) ? K1P_ : KOP_;

            // cell A: [inp | h0] @ [W_ih0|W_hh0]^T -> c0,h0 (h0 -> A2buf[0:512])
            gemm_lstm<<<gBig, 64, 0, stream>>>(
                a1h[l], a1l[l], K1P_, w1h[l], w1l[l],
                b_ih0 + (size_t)l * 2048, b_hh0 + (size_t)l * 2048,
                c0, a2h[l], a2l[l], K2P_, nullptr, nullptr, 0);

            // cell B: [h0 | h1] @ [W_ih1|W_hh1]^T -> c1,h1 (h1 -> h1st; clip -> next input)
            gemm_lstm<<<gBig, 64, 0, stream>>>(
                a2h[l], a2l[l], K2P_, w2h[l], w2l[l],
                b_ih1 + (size_t)l * 2048, b_hh1 + (size_t)l * 2048,
                c1, h1h[l], h1l[l], H_, cliph, clipl, clipst);

            // interface projection: out @ W_iface^T
            gemm_plain<<<gIf, 64, 0, stream>>>(
                cliph, clipl, clipst, wifh[l], wifl[l], H_, H_,
                biasif + (size_t)l * IFP_, ifacev, IFP_);

            mem_step<<<B_, 64, 0, stream>>>(
                ifacev,
                memv + (size_t)l * B_ * M_ * WC_,
                linkv + (size_t)l * B_ * M_ * M_,
                precv + (size_t)l * B_ * M_,
                rwv + (size_t)l * B_ * R_ * M_,
                wwv + (size_t)l * B_ * M_,
                usagev + (size_t)l * B_ * M_,
                cliph, clipl, clipst,
                a1h[l], a1l[l], a2h[l], a2l[l], h1h[l], h1l[l]);
        }
        // y_t = [out1 | rv1] @ W_out^T + b_out
        gemm_plain<<<gOut, 64, 0, stream>>>(
            yinh, yinl, KOP_, wouth, woutl, KOP_, KOP_,
            b_out, out + (size_t)t * IN_, T_ * IN_);
    }
}

// Round 5
// 3893.150 us; speedup vs baseline: 6.2079x; 3.0581x over previous
//
#include <hip/hip_runtime.h>
#include <hip/hip_bf16.h>
#include <math.h>

#define B_ 128
#define T_ 32
#define IN_ 512
#define H_ 512
#define M_ 16
#define WC_ 20
#define R_ 4
#define RW_ 80
#define NNIN_ 592
#define IFACE_ 163
#define IFP_ 192      // iface N padded to 192 (6 tiles of 32)
#define K1P_ 1120     // 592+512 -> 1120 (mult of 16)
#define K2P_ 1024
#define KOP_ 608      // 592 -> 608
#define CLIP_ 20.0f
#define EPS_ 1e-6f
#define DELTA_ 5e-6f

typedef __bf16 bf16x8 __attribute__((ext_vector_type(8)));
typedef float f32x16 __attribute__((ext_vector_type(16)));

__device__ __forceinline__ float sigmoidf_(float x) { return 1.0f / (1.0f + expf(-x)); }
__device__ __forceinline__ float softplusf_(float x) {
    return fmaxf(x, 0.0f) + log1pf(expf(-fabsf(x)));
}
__device__ __forceinline__ void split2(float v, __bf16* hp, __bf16* lp) {
    __bf16 h = (__bf16)v;
    *hp = h;
    *lp = (__bf16)(v - (float)h);
}

// ---------------------------------------------------------------------------
// Weight conversion: dst[n][k] (k<K1: src1, k<K1+K2: src2, else 0) -> hi/lo
// ---------------------------------------------------------------------------
__global__ __launch_bounds__(256) void conv_split(
    const float* __restrict__ s1, int K1, const float* __restrict__ s2, int K2,
    int Nsrc, __bf16* __restrict__ hi, __bf16* __restrict__ lo, int Kd)
{
    int k = blockIdx.x * 256 + threadIdx.x;
    int n = blockIdx.y;
    if (k >= Kd) return;
    float v = 0.f;
    if (n < Nsrc) {
        if (k < K1) v = s1[(size_t)n * K1 + k];
        else if (k < K1 + K2) v = s2[(size_t)n * K2 + (k - K1)];
    }
    __bf16 h = (__bf16)v;
    hi[(size_t)n * Kd + k] = h;
    lo[(size_t)n * Kd + k] = (__bf16)(v - (float)h);
}

__global__ __launch_bounds__(192) void conv_biasif(const float* __restrict__ b_iface,
                                                   float* __restrict__ dst)
{
    int l = blockIdx.x, k = threadIdx.x;
    dst[l * IFP_ + k] = (k < IFACE_) ? b_iface[l * IFACE_ + k] : 0.f;
}

// ---------------------------------------------------------------------------
// x_t -> a1[0] cols [0,512) as bf16 hi/lo
// ---------------------------------------------------------------------------
__global__ __launch_bounds__(256) void build_inp(const float* __restrict__ x, int t,
                                                 __bf16* __restrict__ a1h,
                                                 __bf16* __restrict__ a1l)
{
    int idx = blockIdx.x * 256 + threadIdx.x;
    if (idx >= B_ * IN_) return;
    int b = idx >> 9, j = idx & 511;
    float v = x[(size_t)b * T_ * IN_ + (size_t)t * IN_ + j];
    __bf16 h = (__bf16)v;
    a1h[b * K1P_ + j] = h;
    a1l[b * K1P_ + j] = (__bf16)(v - (float)h);
}

// ---------------------------------------------------------------------------
// Gate GEMM: grid (16 coltiles, 4 batchtiles, 4 gates), 256 thr = 4 waves
// splitting K. Split-bf16 3-pass MFMA 32x32x16. LDS reduce, wave0 stores
// gates fp32 (+bias).
// ---------------------------------------------------------------------------
__global__ __launch_bounds__(256) void gemm_gate(
    const __bf16* __restrict__ Ah, const __bf16* __restrict__ Al, const int KS,
    const __bf16* __restrict__ Wh, const __bf16* __restrict__ Wl,
    const int nsteps,
    const float* __restrict__ b1, const float* __restrict__ b2,
    float* __restrict__ gates)
{
    const int tid = threadIdx.x;
    const int wave = tid >> 6, lane = tid & 63;
    const int l31 = lane & 31, lhi = lane >> 5;
    const int j0 = blockIdx.x * 32;
    const int m0 = blockIdx.y * 32;
    const int z  = blockIdx.z;
    const int ncol = z * 512 + j0 + l31;

    f32x16 acc;
    #pragma unroll
    for (int i = 0; i < 16; ++i) acc[i] = 0.f;

    const int ks = (wave * nsteps) >> 2;
    const int ke = ((wave + 1) * nsteps) >> 2;

    size_t aoff = (size_t)(m0 + l31) * KS + ks * 16 + lhi * 8;
    size_t woff = (size_t)ncol * KS + ks * 16 + lhi * 8;

    for (int s = ks; s < ke; ++s) {
        bf16x8 ah = *(const bf16x8*)(Ah + aoff);
        bf16x8 al = *(const bf16x8*)(Al + aoff);
        bf16x8 wh = *(const bf16x8*)(Wh + woff);
        bf16x8 wl = *(const bf16x8*)(Wl + woff);
        aoff += 16; woff += 16;
        acc = __builtin_amdgcn_mfma_f32_32x32x16_bf16(ah, wh, acc, 0, 0, 0);
        acc = __builtin_amdgcn_mfma_f32_32x32x16_bf16(al, wh, acc, 0, 0, 0);
        acc = __builtin_amdgcn_mfma_f32_32x32x16_bf16(ah, wl, acc, 0, 0, 0);
    }

    __shared__ float red[3][16][64];
    if (wave > 0) {
        #pragma unroll
        for (int r = 0; r < 16; ++r) red[wave - 1][r][lane] = acc[r];
    }
    __syncthreads();
    if (wave == 0) {
        const float bc = b1[ncol] + b2[ncol];
        #pragma unroll
        for (int r = 0; r < 16; ++r) {
            float v = acc[r] + red[0][r][lane] + red[1][r][lane] + red[2][r][lane] + bc;
            const int row = (r & 3) + 8 * (r >> 2) + 4 * lhi;
            gates[(size_t)(m0 + row) * 2048 + ncol] = v;
        }
    }
}

// ---------------------------------------------------------------------------
// LSTM pointwise: gates (B x 2048) -> c update; h -> two bf16 hi/lo dests
// (dest2 optionally clipped)
// ---------------------------------------------------------------------------
__global__ __launch_bounds__(256) void lstm_point(
    const float* __restrict__ g, float* __restrict__ c,
    __bf16* __restrict__ d1h, __bf16* __restrict__ d1l, int st1, int off1,
    __bf16* __restrict__ d2h, __bf16* __restrict__ d2l, int st2, int off2,
    int clip2)
{
    int idx = blockIdx.x * 256 + threadIdx.x;
    if (idx >= B_ * H_) return;
    int b = idx >> 9, j = idx & 511;
    const float* gr = g + (size_t)b * 2048;
    float gi = gr[j];
    float gf = gr[j + 512];
    float gg = gr[j + 1024];
    float go = gr[j + 1536];
    float cn = sigmoidf_(gf) * c[idx] + sigmoidf_(gi) * tanhf(gg);
    c[idx] = cn;
    float h = sigmoidf_(go) * tanhf(cn);
    split2(h, &d1h[(size_t)b * st1 + off1 + j], &d1l[(size_t)b * st1 + off1 + j]);
    float h2 = clip2 ? fminf(fmaxf(h, -CLIP_), CLIP_) : h;
    split2(h2, &d2h[(size_t)b * st2 + off2 + j], &d2l[(size_t)b * st2 + off2 + j]);
}

// ---------------------------------------------------------------------------
// Plain GEMM (iface/out): 4 waves split K, LDS reduce, wave0 stores fp32+bias
// ---------------------------------------------------------------------------
__global__ __launch_bounds__(256) void gemm_plain(
    const __bf16* __restrict__ Ah, const __bf16* __restrict__ Al, const int AS,
    const __bf16* __restrict__ Wh, const __bf16* __restrict__ Wl, const int WS,
    const int nsteps, const float* __restrict__ bias,
    float* __restrict__ C, const int ldc)
{
    const int tid = threadIdx.x;
    const int wave = tid >> 6, lane = tid & 63;
    const int l31 = lane & 31, lhi = lane >> 5;
    const int n0 = blockIdx.x * 32;
    const int m0 = blockIdx.y * 32;

    f32x16 acc;
    #pragma unroll
    for (int i = 0; i < 16; ++i) acc[i] = 0.f;

    const int ks = (wave * nsteps) >> 2;
    const int ke = ((wave + 1) * nsteps) >> 2;

    size_t aoff = (size_t)(m0 + l31) * AS + ks * 16 + lhi * 8;
    size_t woff = (size_t)(n0 + l31) * WS + ks * 16 + lhi * 8;

    for (int s = ks; s < ke; ++s) {
        bf16x8 ah = *(const bf16x8*)(Ah + aoff);
        bf16x8 al = *(const bf16x8*)(Al + aoff);
        bf16x8 wh = *(const bf16x8*)(Wh + woff);
        bf16x8 wl = *(const bf16x8*)(Wl + woff);
        aoff += 16; woff += 16;
        acc = __builtin_amdgcn_mfma_f32_32x32x16_bf16(ah, wh, acc, 0, 0, 0);
        acc = __builtin_amdgcn_mfma_f32_32x32x16_bf16(al, wh, acc, 0, 0, 0);
        acc = __builtin_amdgcn_mfma_f32_32x32x16_bf16(ah, wl, acc, 0, 0, 0);
    }

    __shared__ float red[3][16][64];
    if (wave > 0) {
        #pragma unroll
        for (int r = 0; r < 16; ++r) red[wave - 1][r][lane] = acc[r];
    }
    __syncthreads();
    if (wave == 0) {
        const float bc = bias[n0 + l31];
        #pragma unroll
        for (int r = 0; r < 16; ++r) {
            float v = acc[r] + red[0][r][lane] + red[1][r][lane] + red[2][r][lane] + bc;
            const int row = (r & 3) + 8 * (r >> 2) + 4 * lhi;
            C[(size_t)(m0 + row) * ldc + n0 + l31] = v;
        }
    }
}

// ---------------------------------------------------------------------------
// DNC memory step: one wave per batch element
// ---------------------------------------------------------------------------
__global__ __launch_bounds__(64) void mem_step(
    const float* __restrict__ iface,
    float* __restrict__ mem, float* __restrict__ link, float* __restrict__ prec,
    float* __restrict__ rw, float* __restrict__ ww, float* __restrict__ usage,
    __bf16* __restrict__ dsth, __bf16* __restrict__ dstl, int dstst)
{
    const int b = blockIdx.x;
    const int tid = threadIdx.x;

    __shared__ float sif[IFACE_];
    __shared__ float modes[R_][3];
    __shared__ float us[M_], wwold[M_], wwnew[M_], precold[M_];
    __shared__ float rwold[R_][M_], rwnewS[R_][M_];
    __shared__ float lnk[M_][M_];
    __shared__ float memS[M_][WC_];
    __shared__ float wcw[M_], allocS[M_], rcw[R_][M_];
    __shared__ float uu[M_];
    __shared__ int   phi[M_];
    __shared__ float sumww;

    const float* ifr = iface + (size_t)b * IFP_;
    for (int i = tid; i < IFACE_; i += 64) {
        float v = ifr[i];
        float r;
        if (i < 80)        r = tanhf(v);
        else if (i < 84)   r = softplusf_(v);
        else if (i < 104)  r = tanhf(v);
        else if (i < 105)  r = softplusf_(v);
        else if (i < 125)  r = sigmoidf_(v);
        else if (i < 145)  r = tanhf(v);
        else if (i < 149)  r = sigmoidf_(v);
        else if (i < 151)  r = sigmoidf_(v);
        else               r = v;
        sif[i] = r;
    }
    if (tid < M_) {
        us[tid]      = usage[(size_t)b * M_ + tid];
        wwold[tid]   = ww[(size_t)b * M_ + tid];
        precold[tid] = prec[(size_t)b * M_ + tid];
    }
    for (int i = tid; i < R_ * M_; i += 64) rwold[i >> 4][i & 15] = rw[(size_t)b * R_ * M_ + i];
    for (int i = tid; i < M_ * M_; i += 64) lnk[i >> 4][i & 15] = link[(size_t)b * M_ * M_ + i];
    for (int i = tid; i < M_ * WC_; i += 64) memS[i / WC_][i % WC_] = mem[(size_t)b * M_ * WC_ + i];
    __syncthreads();

    if (tid < R_) {
        float a0 = sif[151 + tid * 3], a1 = sif[152 + tid * 3], a2 = sif[153 + tid * 3];
        float mx = fmaxf(a0, fmaxf(a1, a2));
        float e0 = expf(a0 - mx), e1 = expf(a1 - mx), e2 = expf(a2 - mx);
        float s = e0 + e1 + e2;
        modes[tid][0] = e0 / s; modes[tid][1] = e1 / s; modes[tid][2] = e2 / s;
    }
    if (tid < M_) {
        float u = us[tid];
        u = u + (1.f - u) * wwold[tid];
        float psi = 1.f;
        #pragma unroll
        for (int r = 0; r < R_; ++r) psi *= (1.f - sif[145 + r] * rwold[r][tid]);
        u *= psi;
        us[tid] = u;
    }
    if (tid < M_) {
        float kn2 = 0.f, mn2 = 0.f, dot = 0.f;
        #pragma unroll
        for (int w = 0; w < WC_; ++w) {
            float kv = sif[84 + w], mv = memS[tid][w];
            kn2 += kv * kv; mn2 += mv * mv; dot += kv * mv;
        }
        float c = dot / ((sqrtf(kn2) + EPS_) * (sqrtf(mn2) + EPS_));
        wcw[tid] = c * sif[104];
    }
    __syncthreads();

    if (tid == 0) {
        float mx = -1e30f;
        for (int m = 0; m < M_; ++m) mx = fmaxf(mx, wcw[m]);
        float s = 0.f;
        for (int m = 0; m < M_; ++m) { wcw[m] = expf(wcw[m] - mx); s += wcw[m]; }
        for (int m = 0; m < M_; ++m) wcw[m] /= s;
        for (int m = 0; m < M_; ++m) { uu[m] = DELTA_ + (1.f - DELTA_) * us[m]; phi[m] = m; }
        for (int j = 1; j < M_; ++j) {
            float key = uu[j]; int kp = phi[j];
            int i2 = j - 1;
            while (i2 >= 0 && uu[i2] > key) { uu[i2 + 1] = uu[i2]; phi[i2 + 1] = phi[i2]; --i2; }
            uu[i2 + 1] = key; phi[i2 + 1] = kp;
        }
        float prod = 1.f;
        for (int j = 0; j < M_; ++j) {
            float sa = (1.f - uu[j]) * prod;
            prod *= uu[j];
            allocS[phi[j]] = sa;
        }
    }
    __syncthreads();

    if (tid < M_) {
        wwnew[tid] = sif[150] * (sif[149] * allocS[tid] + (1.f - sif[149]) * wcw[tid]);
    }
    __syncthreads();

    if (tid == 0) {
        float s = 0.f;
        for (int m = 0; m < M_; ++m) s += wwnew[m];
        sumww = s;
    }
    for (int i = tid; i < M_ * WC_; i += 64) {
        int m = i / WC_, w = i % WC_;
        float nm = memS[m][w] * (1.f - wwnew[m] * sif[105 + w]) + wwnew[m] * sif[125 + w];
        memS[m][w] = nm;
        mem[(size_t)b * M_ * WC_ + i] = nm;
    }
    __syncthreads();

    for (int idx = tid; idx < M_ * M_; idx += 64) {
        int i = idx >> 4, j = idx & 15;
        float v = (1.f - wwnew[i] - wwnew[j]) * lnk[i][j] + wwnew[i] * precold[j];
        if (i == j) v = 0.f;
        lnk[i][j] = v;
        link[(size_t)b * M_ * M_ + idx] = v;
    }
    if (tid < M_) {
        prec[(size_t)b * M_ + tid] = (1.f - sumww) * precold[tid] + wwnew[tid];
        usage[(size_t)b * M_ + tid] = us[tid];
        ww[(size_t)b * M_ + tid] = wwnew[tid];
    }
    __syncthreads();

    {
        int r = tid >> 4, m = tid & 15;
        float kn2 = 0.f, mn2 = 0.f, dot = 0.f;
        #pragma unroll
        for (int w = 0; w < WC_; ++w) {
            float kv = sif[r * WC_ + w], mv = memS[m][w];
            kn2 += kv * kv; mn2 += mv * mv; dot += kv * mv;
        }
        float c = dot / ((sqrtf(kn2) + EPS_) * (sqrtf(mn2) + EPS_));
        rcw[r][m] = c * sif[80 + r];
    }
    __syncthreads();
    if (tid < R_) {
        float mx = -1e30f;
        for (int m = 0; m < M_; ++m) mx = fmaxf(mx, rcw[tid][m]);
        float s = 0.f;
        for (int m = 0; m < M_; ++m) { rcw[tid][m] = expf(rcw[tid][m] - mx); s += rcw[tid][m]; }
        for (int m = 0; m < M_; ++m) rcw[tid][m] /= s;
    }
    __syncthreads();

    {
        int r = tid >> 4, m = tid & 15;
        float fwd = 0.f, bwd = 0.f;
        #pragma unroll
        for (int j = 0; j < M_; ++j) fwd += lnk[m][j] * rwold[r][j];
        #pragma unroll
        for (int i = 0; i < M_; ++i) bwd += rwold[r][i] * lnk[i][m];
        float v = modes[r][0] * bwd + modes[r][1] * fwd + modes[r][2] * rcw[r][m];
        rwnewS[r][m] = v;
        rw[(size_t)b * R_ * M_ + tid] = v;
    }
    __syncthreads();

    for (int i = tid; i < RW_; i += 64) {
        int r = i / WC_, w = i - r * WC_;
        float s = 0.f;
        #pragma unroll
        for (int m = 0; m < M_; ++m) s += rwnewS[r][m] * memS[m][w];
        split2(s, &dsth[(size_t)b * dstst + IN_ + i], &dstl[(size_t)b * dstst + IN_ + i]);
    }
}

// ---------------------------------------------------------------------------
extern "C" void kernel_launch(void* const* d_in, const int* in_sizes, int n_in,
                              void* d_out, int out_size, void* d_ws, size_t ws_size,
                              hipStream_t stream)
{
    const float* x       = (const float*)d_in[0];
    const float* W_ih0   = (const float*)d_in[1];
    const float* W_hh0   = (const float*)d_in[2];
    const float* b_ih0   = (const float*)d_in[3];
    const float* b_hh0   = (const float*)d_in[4];
    const float* W_ih1   = (const float*)d_in[5];
    const float* W_hh1   = (const float*)d_in[6];
    const float* b_ih1   = (const float*)d_in[7];
    const float* b_hh1   = (const float*)d_in[8];
    const float* W_iface = (const float*)d_in[9];
    const float* b_iface = (const float*)d_in[10];
    const float* W_out   = (const float*)d_in[11];
    const float* b_out   = (const float*)d_in[12];
    float* out = (float*)d_out;

    char* p = (char*)d_ws;
    auto alloc = [&](size_t bytes) { char* r = p; p += (bytes + 255) & ~(size_t)255; return r; };

    // ---- zero zone (memset each call) ----
    char* zstart = p;
    __bf16* a1h[2]; __bf16* a1l[2]; __bf16* a2h[2]; __bf16* a2l[2];
    for (int l = 0; l < 2; ++l) { a1h[l] = (__bf16*)alloc(B_ * K1P_ * 2); a1l[l] = (__bf16*)alloc(B_ * K1P_ * 2); }
    for (int l = 0; l < 2; ++l) { a2h[l] = (__bf16*)alloc(B_ * K2P_ * 2); a2l[l] = (__bf16*)alloc(B_ * K2P_ * 2); }
    __bf16* yinh = (__bf16*)alloc(B_ * KOP_ * 2);
    __bf16* yinl = (__bf16*)alloc(B_ * KOP_ * 2);
    float* cbuf   = (float*)alloc(4ull * B_ * H_ * 4);
    float* memv   = (float*)alloc(2ull * B_ * M_ * WC_ * 4);
    float* linkv  = (float*)alloc(2ull * B_ * M_ * M_ * 4);
    float* precv  = (float*)alloc(2ull * B_ * M_ * 4);
    float* rwv    = (float*)alloc(2ull * B_ * R_ * M_ * 4);
    float* wwv    = (float*)alloc(2ull * B_ * M_ * 4);
    float* usagev = (float*)alloc(2ull * B_ * M_ * 4);
    size_t zbytes = (size_t)(p - zstart);

    // ---- non-zero scratch ----
    float* gates  = (float*)alloc((size_t)B_ * 2048 * 4);
    float* ifacev = (float*)alloc(B_ * IFP_ * 4);
    __bf16* w1h[2]; __bf16* w1l[2]; __bf16* w2h[2]; __bf16* w2l[2];
    __bf16* wifh[2]; __bf16* wifl[2];
    for (int l = 0; l < 2; ++l) { w1h[l] = (__bf16*)alloc(2048ull * K1P_ * 2); w1l[l] = (__bf16*)alloc(2048ull * K1P_ * 2); }
    for (int l = 0; l < 2; ++l) { w2h[l] = (__bf16*)alloc(2048ull * K2P_ * 2); w2l[l] = (__bf16*)alloc(2048ull * K2P_ * 2); }
    for (int l = 0; l < 2; ++l) { wifh[l] = (__bf16*)alloc((size_t)IFP_ * 512 * 2); wifl[l] = (__bf16*)alloc((size_t)IFP_ * 512 * 2); }
    __bf16* wouth = (__bf16*)alloc(512ull * KOP_ * 2);
    __bf16* woutl = (__bf16*)alloc(512ull * KOP_ * 2);
    float* biasif = (float*)alloc(2ull * IFP_ * 4);

    hipMemsetAsync(zstart, 0, zbytes, stream);

    for (int l = 0; l < 2; ++l) {
        conv_split<<<dim3((K1P_ + 255) / 256, 2048), 256, 0, stream>>>(
            W_ih0 + (size_t)l * 2048 * NNIN_, NNIN_, W_hh0 + (size_t)l * 2048 * H_, H_,
            2048, w1h[l], w1l[l], K1P_);
        conv_split<<<dim3((K2P_ + 255) / 256, 2048), 256, 0, stream>>>(
            W_ih1 + (size_t)l * 2048 * H_, H_, W_hh1 + (size_t)l * 2048 * H_, H_,
            2048, w2h[l], w2l[l], K2P_);
        conv_split<<<dim3(2, IFP_), 256, 0, stream>>>(
            W_iface + (size_t)l * IFACE_ * H_, H_, nullptr, 0,
            IFACE_, wifh[l], wifl[l], H_);
    }
    conv_split<<<dim3((KOP_ + 255) / 256, 512), 256, 0, stream>>>(
        W_out, NNIN_, nullptr, 0, 512, wouth, woutl, KOP_);
    conv_biasif<<<2, 192, 0, stream>>>(b_iface, biasif);

    const dim3 gGate(16, 4, 4);     // coltiles x batchtiles x gates
    const dim3 gIf(6, 4), gOut(16, 4);
    const int pBlocks = (B_ * H_) / 256;

    for (int t = 0; t < T_; ++t) {
        build_inp<<<(B_ * IN_ + 255) / 256, 256, 0, stream>>>(x, t, a1h[0], a1l[0]);
        for (int l = 0; l < 2; ++l) {
            float* c0 = cbuf + (size_t)(l * 2 + 0) * B_ * H_;
            float* c1 = cbuf + (size_t)(l * 2 + 1) * B_ * H_;
            __bf16* cliph = (l == 0) ? a1h[1] : yinh;
            __bf16* clipl = (l == 0) ? a1l[1] : yinl;
            const int clipst = (l == 0) ? K1P_ : KOP_;

            // cell A: gates = [inp | h0] @ [W_ih0|W_hh0]^T
            gemm_gate<<<gGate, 256, 0, stream>>>(
                a1h[l], a1l[l], K1P_, w1h[l], w1l[l], K1P_ / 16,
                b_ih0 + (size_t)l * 2048, b_hh0 + (size_t)l * 2048, gates);
            // h0 -> a2[l][0:512), a1[l][592:1104)
            lstm_point<<<pBlocks, 256, 0, stream>>>(
                gates, c0,
                a2h[l], a2l[l], K2P_, 0,
                a1h[l], a1l[l], K1P_, NNIN_, 0);

            // cell B: gates = [h0 | h1] @ [W_ih1|W_hh1]^T
            gemm_gate<<<gGate, 256, 0, stream>>>(
                a2h[l], a2l[l], K2P_, w2h[l], w2l[l], K2P_ / 16,
                b_ih1 + (size_t)l * 2048, b_hh1 + (size_t)l * 2048, gates);
            // h1 -> a2[l][512:1024); clip(h1) -> next input buffer
            lstm_point<<<pBlocks, 256, 0, stream>>>(
                gates, c1,
                a2h[l], a2l[l], K2P_, H_,
                cliph, clipl, clipst, 0, 1);

            gemm_plain<<<gIf, 256, 0, stream>>>(
                cliph, clipl, clipst, wifh[l], wifl[l], H_, H_ / 16,
                biasif + (size_t)l * IFP_, ifacev, IFP_);

            mem_step<<<B_, 64, 0, stream>>>(
                ifacev,
                memv + (size_t)l * B_ * M_ * WC_,
                linkv + (size_t)l * B_ * M_ * M_,
                precv + (size_t)l * B_ * M_,
                rwv + (size_t)l * B_ * R_ * M_,
                wwv + (size_t)l * B_ * M_,
                usagev + (size_t)l * B_ * M_,
                cliph, clipl, clipst);
        }
        gemm_plain<<<gOut, 256, 0, stream>>>(
            yinh, yinl, KOP_, wouth, woutl, KOP_, KOP_ / 16,
            b_out, out + (size_t)t * IN_, T_ * IN_);
    }
}

// Round 6
// 3524.889 us; speedup vs baseline: 6.8565x; 1.1045x over previous
//
#include <hip/hip_runtime.h>
#include <hip/hip_bf16.h>
#include <math.h>

#define B_ 128
#define T_ 32
#define IN_ 512
#define H_ 512
#define M_ 16
#define WC_ 20
#define R_ 4
#define RW_ 80
#define NNIN_ 592
#define IFACE_ 163
#define IFP_ 192
#define K1P_ 1120
#define K2P_ 1024
#define KOP_ 608
#define CLIP_ 20.0f
#define EPS_ 1e-6f
#define DELTA_ 5e-6f

typedef __bf16 bf16x8 __attribute__((ext_vector_type(8)));
typedef float f32x4 __attribute__((ext_vector_type(4)));

__device__ __forceinline__ float sigmoidf_(float x) { return 1.0f / (1.0f + expf(-x)); }
__device__ __forceinline__ float softplusf_(float x) {
    return fmaxf(x, 0.0f) + log1pf(expf(-fabsf(x)));
}
__device__ __forceinline__ void split2(float v, __bf16* hp, __bf16* lp) {
    __bf16 h = (__bf16)v;
    *hp = h;
    *lp = (__bf16)(v - (float)h);
}

__global__ __launch_bounds__(256) void conv_split(
    const float* __restrict__ s1, int K1, const float* __restrict__ s2, int K2,
    int Nsrc, __bf16* __restrict__ hi, __bf16* __restrict__ lo, int Kd)
{
    int k = blockIdx.x * 256 + threadIdx.x;
    int n = blockIdx.y;
    if (k >= Kd) return;
    float v = 0.f;
    if (n < Nsrc) {
        if (k < K1) v = s1[(size_t)n * K1 + k];
        else if (k < K1 + K2) v = s2[(size_t)n * K2 + (k - K1)];
    }
    __bf16 h = (__bf16)v;
    hi[(size_t)n * Kd + k] = h;
    lo[(size_t)n * Kd + k] = (__bf16)(v - (float)h);
}

__global__ __launch_bounds__(192) void conv_biasif(const float* __restrict__ b_iface,
                                                   float* __restrict__ dst)
{
    int l = blockIdx.x, k = threadIdx.x;
    dst[l * IFP_ + k] = (k < IFACE_) ? b_iface[l * IFACE_ + k] : 0.f;
}

__global__ __launch_bounds__(256) void build_inp(const float* __restrict__ x, int t,
                                                 __bf16* __restrict__ a1h,
                                                 __bf16* __restrict__ a1l)
{
    int idx = blockIdx.x * 256 + threadIdx.x;
    if (idx >= B_ * IN_) return;
    int b = idx >> 9, j = idx & 511;
    float v = x[(size_t)b * T_ * IN_ + (size_t)t * IN_ + j];
    __bf16 h = (__bf16)v;
    a1h[b * K1P_ + j] = h;
    a1l[b * K1P_ + j] = (__bf16)(v - (float)h);
}

// Fused LSTM GEMM+pointwise: 16x16x32 MFMA, block = 16x16 (batch x hidden)
// tile of ALL 4 gates; 4 waves split K; wave0 does LSTM epilogue.
__global__ __launch_bounds__(256) void gemm_lstm16(
    const __bf16* __restrict__ Ah, const __bf16* __restrict__ Al, const int KS,
    const __bf16* __restrict__ Wh, const __bf16* __restrict__ Wl,
    const int nsteps,
    const float* __restrict__ b1, const float* __restrict__ b2,
    float* __restrict__ cst,
    __bf16* __restrict__ d1h, __bf16* __restrict__ d1l, int st1, int off1,
    __bf16* __restrict__ d2h, __bf16* __restrict__ d2l, int st2, int off2,
    int clip2)
{
    const int tid = threadIdx.x;
    const int wave = tid >> 6, lane = tid & 63;
    const int l15 = lane & 15, quad = lane >> 4;
    const int j0 = blockIdx.x * 16;
    const int m0 = blockIdx.y * 16;

    f32x4 acc[4];
    #pragma unroll
    for (int g = 0; g < 4; ++g)
        #pragma unroll
        for (int i = 0; i < 4; ++i) acc[g][i] = 0.f;

    const int ks = (wave * nsteps) >> 2;
    const int ke = ((wave + 1) * nsteps) >> 2;

    size_t aoff = (size_t)(m0 + l15) * KS + ks * 32 + quad * 8;
    size_t woff[4];
    #pragma unroll
    for (int g = 0; g < 4; ++g)
        woff[g] = (size_t)(g * 512 + j0 + l15) * KS + ks * 32 + quad * 8;

    for (int s = ks; s < ke; ++s) {
        bf16x8 ah = *(const bf16x8*)(Ah + aoff);
        bf16x8 al = *(const bf16x8*)(Al + aoff);
        aoff += 32;
        #pragma unroll
        for (int g = 0; g < 4; ++g) {
            bf16x8 wh = *(const bf16x8*)(Wh + woff[g]);
            bf16x8 wl = *(const bf16x8*)(Wl + woff[g]);
            woff[g] += 32;
            acc[g] = __builtin_amdgcn_mfma_f32_16x16x32_bf16(ah, wh, acc[g], 0, 0, 0);
            acc[g] = __builtin_amdgcn_mfma_f32_16x16x32_bf16(al, wh, acc[g], 0, 0, 0);
            acc[g] = __builtin_amdgcn_mfma_f32_16x16x32_bf16(ah, wl, acc[g], 0, 0, 0);
        }
    }

    __shared__ float red[16][3][64];
    if (wave > 0) {
        #pragma unroll
        for (int g = 0; g < 4; ++g)
            #pragma unroll
            for (int r = 0; r < 4; ++r)
                red[g * 4 + r][wave - 1][lane] = acc[g][r];
    }
    __syncthreads();
    if (wave == 0) {
        const int col = j0 + l15;
        float bg[4];
        #pragma unroll
        for (int g = 0; g < 4; ++g) bg[g] = b1[g * 512 + col] + b2[g * 512 + col];
        #pragma unroll
        for (int r = 0; r < 4; ++r) {
            const int m = m0 + quad * 4 + r;
            float gv[4];
            #pragma unroll
            for (int g = 0; g < 4; ++g) {
                int i = g * 4 + r;
                gv[g] = acc[g][r] + red[i][0][lane] + red[i][1][lane] + red[i][2][lane] + bg[g];
            }
            float cold = cst[m * H_ + col];
            float cn = sigmoidf_(gv[1]) * cold + sigmoidf_(gv[0]) * tanhf(gv[2]);
            cst[m * H_ + col] = cn;
            float h = sigmoidf_(gv[3]) * tanhf(cn);
            split2(h, &d1h[(size_t)m * st1 + off1 + col], &d1l[(size_t)m * st1 + off1 + col]);
            float h2 = clip2 ? fminf(fmaxf(h, -CLIP_), CLIP_) : h;
            split2(h2, &d2h[(size_t)m * st2 + off2 + col], &d2l[(size_t)m * st2 + off2 + col]);
        }
    }
}

__global__ __launch_bounds__(256) void gemm_plain16(
    const __bf16* __restrict__ Ah, const __bf16* __restrict__ Al, const int AS,
    const __bf16* __restrict__ Wh, const __bf16* __restrict__ Wl, const int WS,
    const int nsteps, const float* __restrict__ bias,
    float* __restrict__ C, const int ldc)
{
    const int tid = threadIdx.x;
    const int wave = tid >> 6, lane = tid & 63;
    const int l15 = lane & 15, quad = lane >> 4;
    const int n0 = blockIdx.x * 16;
    const int m0 = blockIdx.y * 16;

    f32x4 acc;
    #pragma unroll
    for (int i = 0; i < 4; ++i) acc[i] = 0.f;

    const int ks = (wave * nsteps) >> 2;
    const int ke = ((wave + 1) * nsteps) >> 2;

    size_t aoff = (size_t)(m0 + l15) * AS + ks * 32 + quad * 8;
    size_t woff = (size_t)(n0 + l15) * WS + ks * 32 + quad * 8;

    for (int s = ks; s < ke; ++s) {
        bf16x8 ah = *(const bf16x8*)(Ah + aoff);
        bf16x8 al = *(const bf16x8*)(Al + aoff);
        bf16x8 wh = *(const bf16x8*)(Wh + woff);
        bf16x8 wl = *(const bf16x8*)(Wl + woff);
        aoff += 32; woff += 32;
        acc = __builtin_amdgcn_mfma_f32_16x16x32_bf16(ah, wh, acc, 0, 0, 0);
        acc = __builtin_amdgcn_mfma_f32_16x16x32_bf16(al, wh, acc, 0, 0, 0);
        acc = __builtin_amdgcn_mfma_f32_16x16x32_bf16(ah, wl, acc, 0, 0, 0);
    }

    __shared__ float red[4][3][64];
    if (wave > 0) {
        #pragma unroll
        for (int r = 0; r < 4; ++r) red[r][wave - 1][lane] = acc[r];
    }
    __syncthreads();
    if (wave == 0) {
        const int col = n0 + l15;
        const float bc = bias[col];
        #pragma unroll
        for (int r = 0; r < 4; ++r) {
            const int m = m0 + quad * 4 + r;
            float v = acc[r] + red[r][0][lane] + red[r][1][lane] + red[r][2][lane] + bc;
            C[(size_t)m * ldc + col] = v;
        }
    }
}

__global__ __launch_bounds__(64) void mem_step(
    const float* __restrict__ iface,
    float* __restrict__ mem, float* __restrict__ link, float* __restrict__ prec,
    float* __restrict__ rw, float* __restrict__ ww, float* __restrict__ usage,
    __bf16* __restrict__ dsth, __bf16* __restrict__ dstl, int dstst)
{
    const int b = blockIdx.x;
    const int tid = threadIdx.x;

    __shared__ float sif[IFACE_];
    __shared__ float modes[R_][3];
    __shared__ float us[M_], wwold[M_], wwnew[M_], precold[M_];
    __shared__ float rwold[R_][M_], rwnewS[R_][M_];
    __shared__ float lnk[M_][M_];
    __shared__ float memS[M_][WC_];
    __shared__ float wcw[M_], allocS[M_], rcw[R_][M_];
    __shared__ float uu[M_];
    __shared__ int   phi[M_];
    __shared__ float sumww;

    const float* ifr = iface + (size_t)b * IFP_;
    for (int i = tid; i < IFACE_; i += 64) {
        float v = ifr[i];
        float r;
        if (i < 80)        r = tanhf(v);
        else if (i < 84)   r = softplusf_(v);
        else if (i < 104)  r = tanhf(v);
        else if (i < 105)  r = softplusf_(v);
        else if (i < 125)  r = sigmoidf_(v);
        else if (i < 145)  r = tanhf(v);
        else if (i < 149)  r = sigmoidf_(v);
        else if (i < 151)  r = sigmoidf_(v);
        else               r = v;
        sif[i] = r;
    }
    if (tid < M_) {
        us[tid]      = usage[(size_t)b * M_ + tid];
        wwold[tid]   = ww[(size_t)b * M_ + tid];
        precold[tid] = prec[(size_t)b * M_ + tid];
    }
    for (int i = tid; i < R_ * M_; i += 64) rwold[i >> 4][i & 15] = rw[(size_t)b * R_ * M_ + i];
    for (int i = tid; i < M_ * M_; i += 64) lnk[i >> 4][i & 15] = link[(size_t)b * M_ * M_ + i];
    for (int i = tid; i < M_ * WC_; i += 64) memS[i / WC_][i % WC_] = mem[(size_t)b * M_ * WC_ + i];
    __syncthreads();

    if (tid < R_) {
        float a0 = sif[151 + tid * 3], a1 = sif[152 + tid * 3], a2 = sif[153 + tid * 3];
        float mx = fmaxf(a0, fmaxf(a1, a2));
        float e0 = expf(a0 - mx), e1 = expf(a1 - mx), e2 = expf(a2 - mx);
        float s = e0 + e1 + e2;
        modes[tid][0] = e0 / s; modes[tid][1] = e1 / s; modes[tid][2] = e2 / s;
    }
    if (tid < M_) {
        float u = us[tid];
        u = u + (1.f - u) * wwold[tid];
        float psi = 1.f;
        #pragma unroll
        for (int r = 0; r < R_; ++r) psi *= (1.f - sif[145 + r] * rwold[r][tid]);
        u *= psi;
        us[tid] = u;
    }
    if (tid < M_) {
        float kn2 = 0.f, mn2 = 0.f, dot = 0.f;
        #pragma unroll
        for (int w = 0; w < WC_; ++w) {
            float kv = sif[84 + w], mv = memS[tid][w];
            kn2 += kv * kv; mn2 += mv * mv; dot += kv * mv;
        }
        float c = dot / ((sqrtf(kn2) + EPS_) * (sqrtf(mn2) + EPS_));
        wcw[tid] = c * sif[104];
    }
    __syncthreads();

    if (tid == 0) {
        float mx = -1e30f;
        for (int m = 0; m < M_; ++m) mx = fmaxf(mx, wcw[m]);
        float s = 0.f;
        for (int m = 0; m < M_; ++m) { wcw[m] = expf(wcw[m] - mx); s += wcw[m]; }
        for (int m = 0; m < M_; ++m) wcw[m] /= s;
        for (int m = 0; m < M_; ++m) { uu[m] = DELTA_ + (1.f - DELTA_) * us[m]; phi[m] = m; }
        for (int j = 1; j < M_; ++j) {
            float key = uu[j]; int kp = phi[j];
            int i2 = j - 1;
            while (i2 >= 0 && uu[i2] > key) { uu[i2 + 1] = uu[i2]; phi[i2 + 1] = phi[i2]; --i2; }
            uu[i2 + 1] = key; phi[i2 + 1] = kp;
        }
        float prod = 1.f;
        for (int j = 0; j < M_; ++j) {
            float sa = (1.f - uu[j]) * prod;
            prod *= uu[j];
            allocS[phi[j]] = sa;
        }
    }
    __syncthreads();

    if (tid < M_) {
        wwnew[tid] = sif[150] * (sif[149] * allocS[tid] + (1.f - sif[149]) * wcw[tid]);
    }
    __syncthreads();

    if (tid == 0) {
        float s = 0.f;
        for (int m = 0; m < M_; ++m) s += wwnew[m];
        sumww = s;
    }
    for (int i = tid; i < M_ * WC_; i += 64) {
        int m = i / WC_, w = i % WC_;
        float nm = memS[m][w] * (1.f - wwnew[m] * sif[105 + w]) + wwnew[m] * sif[125 + w];
        memS[m][w] = nm;
        mem[(size_t)b * M_ * WC_ + i] = nm;
    }
    __syncthreads();

    for (int idx = tid; idx < M_ * M_; idx += 64) {
        int i = idx >> 4, j = idx & 15;
        float v = (1.f - wwnew[i] - wwnew[j]) * lnk[i][j] + wwnew[i] * precold[j];
        if (i == j) v = 0.f;
        lnk[i][j] = v;
        link[(size_t)b * M_ * M_ + idx] = v;
    }
    if (tid < M_) {
        prec[(size_t)b * M_ + tid] = (1.f - sumww) * precold[tid] + wwnew[tid];
        usage[(size_t)b * M_ + tid] = us[tid];
        ww[(size_t)b * M_ + tid] = wwnew[tid];
    }
    __syncthreads();

    {
        int r = tid >> 4, m = tid & 15;
        float kn2 = 0.f, mn2 = 0.f, dot = 0.f;
        #pragma unroll
        for (int w = 0; w < WC_; ++w) {
            float kv = sif[r * WC_ + w], mv = memS[m][w];
            kn2 += kv * kv; mn2 += mv * mv; dot += kv * mv;
        }
        float c = dot / ((sqrtf(kn2) + EPS_) * (sqrtf(mn2) + EPS_));
        rcw[r][m] = c * sif[80 + r];
    }
    __syncthreads();
    if (tid < R_) {
        float mx = -1e30f;
        for (int m = 0; m < M_; ++m) mx = fmaxf(mx, rcw[tid][m]);
        float s = 0.f;
        for (int m = 0; m < M_; ++m) { rcw[tid][m] = expf(rcw[tid][m] - mx); s += rcw[tid][m]; }
        for (int m = 0; m < M_; ++m) rcw[tid][m] /= s;
    }
    __syncthreads();

    {
        int r = tid >> 4, m = tid & 15;
        float fwd = 0.f, bwd = 0.f;
        #pragma unroll
        for (int j = 0; j < M_; ++j) fwd += lnk[m][j] * rwold[r][j];
        #pragma unroll
        for (int i = 0; i < M_; ++i) bwd += rwold[r][i] * lnk[i][m];
        float v = modes[r][0] * bwd + modes[r][1] * fwd + modes[r][2] * rcw[r][m];
        rwnewS[r][m] = v;
        rw[(size_t)b * R_ * M_ + tid] = v;
    }
    __syncthreads();

    for (int i = tid; i < RW_; i += 64) {
        int r = i / WC_, w = i - r * WC_;
        float s = 0.f;
        #pragma unroll
        for (int m = 0; m < M_; ++m) s += rwnewS[r][m] * memS[m][w];
        split2(s, &dsth[(size_t)b * dstst + IN_ + i], &dstl[(size_t)b * dstst + IN_ + i]);
    }
}

extern "C" void kernel_launch(void* const* d_in, const int* in_sizes, int n_in,
                              void* d_out, int out_size, void* d_ws, size_t ws_size,
                              hipStream_t stream)
{
    const float* x       = (const float*)d_in[0];
    const float* W_ih0   = (const float*)d_in[1];
    const float* W_hh0   = (const float*)d_in[2];
    const float* b_ih0   = (const float*)d_in[3];
    const float* b_hh0   = (const float*)d_in[4];
    const float* W_ih1   = (const float*)d_in[5];
    const float* W_hh1   = (const float*)d_in[6];
    const float* b_ih1   = (const float*)d_in[7];
    const float* b_hh1   = (const float*)d_in[8];
    const float* W_iface = (const float*)d_in[9];
    const float* b_iface = (const float*)d_in[10];
    const float* W_out   = (const float*)d_in[11];
    const float* b_out   = (const float*)d_in[12];
    float* out = (float*)d_out;

    char* p = (char*)d_ws;
    auto alloc = [&](size_t bytes) { char* r = p; p += (bytes + 255) & ~(size_t)255; return r; };

    char* zstart = p;
    __bf16* a1h[2]; __bf16* a1l[2]; __bf16* a2h[2]; __bf16* a2l[2];
    for (int l = 0; l < 2; ++l) { a1h[l] = (__bf16*)alloc(B_ * K1P_ * 2); a1l[l] = (__bf16*)alloc(B_ * K1P_ * 2); }
    for (int l = 0; l < 2; ++l) { a2h[l] = (__bf16*)alloc(B_ * K2P_ * 2); a2l[l] = (__bf16*)alloc(B_ * K2P_ * 2); }
    __bf16* yinh = (__bf16*)alloc(B_ * KOP_ * 2);
    __bf16* yinl = (__bf16*)alloc(B_ * KOP_ * 2);
    float* cbuf   = (float*)alloc(4ull * B_ * H_ * 4);
    float* memv   = (float*)alloc(2ull * B_ * M_ * WC_ * 4);
    float* linkv  = (float*)alloc(2ull * B_ * M_ * M_ * 4);
    float* precv  = (float*)alloc(2ull * B_ * M_ * 4);
    float* rwv    = (float*)alloc(2ull * B_ * R_ * M_ * 4);
    float* wwv    = (float*)alloc(2ull * B_ * M_ * 4);
    float* usagev = (float*)alloc(2ull * B_ * M_ * 4);
    size_t zbytes = (size_t)(p - zstart);

    float* ifacev = (float*)alloc(B_ * IFP_ * 4);
    __bf16* w1h[2]; __bf16* w1l[2]; __bf16* w2h[2]; __bf16* w2l[2];
    __bf16* wifh[2]; __bf16* wifl[2];
    for (int l = 0; l < 2; ++l) { w1h[l] = (__bf16*)alloc(2048ull * K1P_ * 2); w1l[l] = (__bf16*)alloc(2048ull * K1P_ * 2); }
    for (int l = 0; l < 2; ++l) { w2h[l] = (__bf16*)alloc(2048ull * K2P_ * 2); w2l[l] = (__bf16*)alloc(2048ull * K2P_ * 2); }
    for (int l = 0; l < 2; ++l) { wifh[l] = (__bf16*)alloc((size_t)IFP_ * 512 * 2); wifl[l] = (__bf16*)alloc((size_t)IFP_ * 512 * 2); }
    __bf16* wouth = (__bf16*)alloc(512ull * KOP_ * 2);
    __bf16* woutl = (__bf16*)alloc(512ull * KOP_ * 2);
    float* biasif = (float*)alloc(2ull * IFP_ * 4);

    hipMemsetAsync(zstart, 0, zbytes, stream);

    for (int l = 0; l < 2; ++l) {
        conv_split<<<dim3((K1P_ + 255) / 256, 2048), 256, 0, stream>>>(
            W_ih0 + (size_t)l * 2048 * NNIN_, NNIN_, W_hh0 + (size_t)l * 2048 * H_, H_,
            2048, w1h[l], w1l[l], K1P_);
        conv_split<<<dim3((K2P_ + 255) / 256, 2048), 256, 0, stream>>>(
            W_ih1 + (size_t)l * 2048 * H_, H_, W_hh1 + (size_t)l * 2048 * H_, H_,
            2048, w2h[l], w2l[l], K2P_);
        conv_split<<<dim3(2, IFP_), 256, 0, stream>>>(
            W_iface + (size_t)l * IFACE_ * H_, H_, nullptr, 0,
            IFACE_, wifh[l], wifl[l], H_);
    }
    conv_split<<<dim3((KOP_ + 255) / 256, 512), 256, 0, stream>>>(
        W_out, NNIN_, nullptr, 0, 512, wouth, woutl, KOP_);
    conv_biasif<<<2, 192, 0, stream>>>(b_iface, biasif);

    const dim3 gGate(32, 8);
    const dim3 gIf(12, 8), gOut(32, 8);

    for (int t = 0; t < T_; ++t) {
        build_inp<<<(B_ * IN_ + 255) / 256, 256, 0, stream>>>(x, t, a1h[0], a1l[0]);
        for (int l = 0; l < 2; ++l) {
            float* c0 = cbuf + (size_t)(l * 2 + 0) * B_ * H_;
            float* c1 = cbuf + (size_t)(l * 2 + 1) * B_ * H_;
            __bf16* cliph = (l == 0) ? a1h[1] : yinh;
            __bf16* clipl = (l == 0) ? a1l[1] : yinl;
            const int clipst = (l == 0) ? K1P_ : KOP_;

            gemm_lstm16<<<gGate, 256, 0, stream>>>(
                a1h[l], a1l[l], K1P_, w1h[l], w1l[l], K1P_ / 32,
                b_ih0 + (size_t)l * 2048, b_hh0 + (size_t)l * 2048,
                c0,
                a2h[l], a2l[l], K2P_, 0,
                a1h[l], a1l[l], K1P_, NNIN_, 0);

            gemm_lstm16<<<gGate, 256, 0, stream>>>(
                a2h[l], a2l[l], K2P_, w2h[l], w2l[l], K2P_ / 32,
                b_ih1 + (size_t)l * 2048, b_hh1 + (size_t)l * 2048,
                c1,
                a2h[l], a2l[l], K2P_, H_,
                cliph, clipl, clipst, 0, 1);

            gemm_plain16<<<gIf, 256, 0, stream>>>(
                cliph, clipl, clipst, wifh[l], wifl[l], H_, H_ / 32,
                biasif + (size_t)l * IFP_, ifacev, IFP_);

            mem_step<<<B_, 64, 0, stream>>>(
                ifacev,
                memv + (size_t)l * B_ * M_ * WC_,
                linkv + (size_t)l * B_ * M_ * M_,
                precv + (size_t)l * B_ * M_,
                rwv + (size_t)l * B_ * R_ * M_,
                wwv + (size_t)l * B_ * M_,
                usagev + (size_t)l * B_ * M_,
                cliph, clipl, clipst);
        }
        gemm_plain16<<<gOut, 256, 0, stream>>>(
            yinh, yinl, KOP_, wouth, woutl, KOP_, KOP_ / 32,
            b_out, out + (size_t)t * IN_, T_ * IN_);
    }
}